// Round 8
// baseline (265.841 us; speedup 1.0000x reference)
//
#include <hip/hip_runtime.h>
#include <math.h>

#define B_ 2
#define S_ 8
#define N_ 150
#define H_ 128
#define F_ 40
#define EF_ 82
#define NP_ 160            // N padded to 10 j-tiles of 16
#define MPQ 136            // mbuf row pitch in bf16 elems (128 + 8 pad)
#define NB_ 2400           // B*S*N

typedef __attribute__((ext_vector_type(8))) short short8;
typedef __attribute__((ext_vector_type(4))) float float4v;

__device__ __forceinline__ float silu_f(float v) {
    return v * __builtin_amdgcn_rcpf(1.0f + __expf(-v));
}

// fp32 -> bf16 bits, round-to-nearest-even (prelude pack; matches v_cvt_pk_bf16_f32)
__device__ __forceinline__ unsigned short f2bf(float f) {
    unsigned u = __builtin_bit_cast(unsigned, f);
    return (unsigned short)((u + 0x7fffu + ((u >> 16) & 1u)) >> 16);
}

// HW RNE pack: lo -> bits[15:0], hi -> bits[31:16]. Identical rounding to f2bf
// for all finite values (both RNE); silu outputs are always finite.
__device__ __forceinline__ unsigned cvt_pk_bf16(float lo, float hi) {
    unsigned r;
    asm("v_cvt_pk_bf16_f32 %0, %1, %2" : "=v"(r) : "v"(lo), "v"(hi));
    return r;
}

// async global->LDS DMA, 16B per lane; LDS dest is wave-uniform base + lane*16,
// global source is per-lane (carries the swizzle).
__device__ __forceinline__ void g2lds16(const float* g, float* l) {
    __builtin_amdgcn_global_load_lds(
        (const __attribute__((address_space(1))) unsigned int*)g,
        (__attribute__((address_space(3))) unsigned int*)l,
        16, 0, 0);
}

// ---------------- prelude: pack_we2 + restore_x + node0 + WhT + W1nT ----------
// blocks [0,192):   pack 3 layers' We2 -> bf16 transposed [c][k]
// blocks [192,221): restore absolute coords (7200 elems)
// blocks [221,371): layer-0 node embedding (2 (b,i) per block)
// blocks [371,424): pack WhT[l][f][k] = W_h[l][k][f]      (2*40*168)
// blocks [424,504): pack W1nT[s][c][k] = We1_s[k][c], k<80 (2*128*80)
__global__ void prelude_kernel(const float* __restrict__ W_e2,
                               const float* __restrict__ tW_e2,
                               unsigned short* __restrict__ we2t,
                               const float* __restrict__ x,
                               const float* __restrict__ R,
                               float* __restrict__ xa,
                               float* __restrict__ x0,
                               const int* __restrict__ pep,
                               const int* __restrict__ labels,
                               const int* __restrict__ aapos,
                               const float* __restrict__ We1,
                               const float* __restrict__ be1,
                               const float* __restrict__ tp,
                               const float* __restrict__ wt,
                               const float* __restrict__ wbt,
                               float* __restrict__ h0,
                               float* __restrict__ Af,
                               float* __restrict__ Bf,
                               const float* __restrict__ W_h,
                               float* __restrict__ whT,
                               const float* __restrict__ We1L1,
                               const float* __restrict__ tWe1,
                               float* __restrict__ w1nT) {
    int bid = blockIdx.x;
    int tid = threadIdx.x;
    if (bid < 192) {
        int e = bid * 256 + tid;                 // 0..49151
        int l = e >> 14, idx = e & 16383;
        int k = idx >> 7, c = idx & 127;
        const float* src = (l == 0) ? W_e2 : (l == 1) ? (W_e2 + H_ * H_) : tW_e2;
        we2t[l * 16384 + c * H_ + k] = f2bf(src[idx]);
    } else if (bid < 221) {
        int idx = (bid - 192) * 256 + tid;
        if (idx < B_ * S_ * N_ * 3) {
            int d = idx % 3;
            int i = (idx / 3) % N_;
            int bs = idx / (3 * N_);
            int b = bs / S_;
            const float* xrow = x + bs * N_ * 3 + d;
            const float* Rrow = R + (b * N_ + i) * N_;
            float acc = 0.0f;
            for (int j = 0; j < N_; j++) acc += xrow[j * 3] * Rrow[j];
            xa[idx] = acc;
            x0[idx] = acc;
        }
    } else if (bid < 371) {
        int rel = bid - 221;                     // 0..149
        int bi = rel * 2 + (tid >> 7);           // 0..299
        int b = bi / N_, i = bi % N_;
        int c = tid & 127;
        int al = labels[bi];
        int ap = aapos[bi];                      // 1..15
        int aa = pep[b * 15 + ap - 1];
        int r0 = al, r1 = 5 + aa, r2 = 25 + ap - 1;
        float fa = We1[r0 * H_ + c] + We1[r1 * H_ + c] + We1[r2 * H_ + c]
                 + be1[c] + tp[b] * wt[c] + wbt[c];
        float fb = We1[(F_ + r0) * H_ + c] + We1[(F_ + r1) * H_ + c] + We1[(F_ + r2) * H_ + c];
        float hv = 0.0f;
        if (c < F_) hv = (c == r0 || c == r1 || c == r2) ? 1.0f : 0.0f;
        for (int s = 0; s < S_; s++) {
            int n = (b * S_ + s) * N_ + i;
            Af[n * H_ + c] = fa;
            Bf[n * H_ + c] = fb;
            if (c < F_) h0[n * F_ + c] = hv;
        }
    } else if (bid < 424) {
        int e = (bid - 371) * 256 + tid;         // 0..13567
        if (e < 2 * F_ * 168) {
            int l = e / 6720, idx = e % 6720;
            int f = idx / 168, k = idx % 168;
            whT[l * 6720 + f * 168 + k] = W_h[l * 6720 + k * F_ + f];
        }
    } else {
        int e = (bid - 424) * 256 + tid;         // 0..20479 exact
        int s = e / 10240, idx = e % 10240;
        int c = idx / 80, k = idx % 80;
        const float* src = s ? tWe1 : We1L1;
        w1nT[s * 10240 + c * 80 + k] = src[k * H_ + c];
    }
}

// ---------------- fused edge + node: block per (bs,i) ----------------
// r7 structure; ONE change: Bfeat tiles are prefetched into LDS via
// global_load_lds (zero added register live-range — the r3/r4/r6 spill class
// was register-held prefetch). Pre-swizzled source (slot^=(row&7), T21) +
// XOR'd ds_read gives conflict-free b128 reads. DMA for tile jt+1 issues
// right after iteration jt's barrier, flies under MFMA+epilogue, and is
// awaited by vmcnt(0) at the next loop top. br values identical f32 ->
// bitwise-identical output.
__global__ __launch_bounds__(256, 4) void edge_fused_kernel(
    const float* __restrict__ x_in,    // [BS*N,3]
    const float* __restrict__ Afeat,   // [BS*N,128]
    const float* __restrict__ Bfeat,   // [BS*N,128]
    const float* __restrict__ We1,     // [82,128] rows 80/81 (dist,bond cols)
    const unsigned short* __restrict__ we2t,  // [128c][128k] bf16
    const float* __restrict__ be2,
    const float* __restrict__ Wc,
    const float* __restrict__ bcp,
    const float* __restrict__ bond,
    const float* __restrict__ emask,
    const float* __restrict__ h_in,    // [BS*N,40]      (node tail)
    const float* __restrict__ whTp,    // [40][168]      (node tail, transposed Wh)
    const float* __restrict__ bh,      // [40]           (node tail)
    const float* __restrict__ w1nTp,   // [128][80]      (next layer We1 rows 0..79, transposed)
    const float* __restrict__ be1n,
    const float* __restrict__ tp,
    const float* __restrict__ wtn,
    const float* __restrict__ wbtn,
    int has_t,
    const float* __restrict__ x0v,     // final mode only
    const float* __restrict__ amask,   // final mode only
    int final_mode,
    float* __restrict__ x_out,         // xnew, or final output
    float* __restrict__ h_out,         // node tail out
    float* __restrict__ Af_out,        // node tail out (next layer)
    float* __restrict__ Bf_out)        // node tail out (next layer)
{
    __shared__ __align__(16) short mbuf[2][16 * MPQ];   // 8.7 KB
    __shared__ __align__(16) float bpref[2][2048];      // 2 x 8KB Bfeat tiles
    __shared__ float4 diffE[NP_];                       // d0,d1,d2,em
    __shared__ float2 dbL[NP_];                         // dist, bond
    __shared__ float DsumL[3];
    __shared__ float wpart[4][3];
    __shared__ float catL[F_ + H_];                     // [h(40), agg(128)]
    __shared__ float partL[120];
    __shared__ float hnewL[F_];

    int blk = blockIdx.x;
    int i = blk % N_, bs = blk / N_, b = bs / S_;
    int tid = threadIdx.x;
    int node = bs * N_ + i;
    int lane = tid & 63, w = tid >> 6;
    int qd = lane >> 4, l15 = lane & 15;
    int rowLoc = tid >> 4, c0 = (tid & 15) * 8;

    float xi0 = x_in[node * 3 + 0];
    float xi1 = x_in[node * 3 + 1];
    float xi2 = x_in[node * 3 + 2];

    // ---- Bfeat panel base + per-thread DMA source swizzle offsets ----
    // slot sigma(d) = d ^ ((d>>5)&7): involution within each 8KB tile.
    const float* bbase = Bfeat + (size_t)(bs * N_) * H_;
    int dI0 = (w * 2) * 64 + lane;          // DMA instr 0 slot index
    int dI1 = dI0 + 64;                     // DMA instr 1 slot index
    int sOffA = (dI0 ^ ((dI0 >> 5) & 7)) << 2;   // float offset
    int sOffB = (dI1 ^ ((dI1 >> 5) & 7)) << 2;
    // per-thread swizzled read offsets (within-tile), loop-invariant
    int rdSlot = (rowLoc * 32 + (tid & 15) * 2) ^ (rowLoc & 7);
    int rdOff0 = rdSlot << 2;
    int rdOff1 = (rdSlot ^ 1) << 2;

    // ---- prefetch tile 0 (drained by the first __syncthreads) ----
    g2lds16(bbase + sOffA, &bpref[0][w * 512]);
    g2lds16(bbase + sOffB, &bpref[0][w * 512 + 256]);

    // ---- stage per-j scalars ----
    if (tid < NP_) {
        int j = tid;
        float xj0 = xi0, xj1 = xi1, xj2 = xi2, bnd = 0.0f, emv = 0.0f;
        if (j < N_) {
            int nj = bs * N_ + j;
            xj0 = x_in[nj * 3 + 0];
            xj1 = x_in[nj * 3 + 1];
            xj2 = x_in[nj * 3 + 2];
            int eij = (b * N_ + i) * N_ + j;
            bnd = bond[eij];
            emv = (j == i) ? 0.0f : emask[eij];
        }
        float d0 = xi0 - xj0, d1 = xi1 - xj1, d2 = xi2 - xj2;
        diffE[j] = make_float4(d0, d1, d2, emv);
        dbL[j] = make_float2(sqrtf(d0 * d0 + d1 * d1 + d2 * d2 + 1e-12f), bnd);
    }

    // ---- hoisted m-compute constants: this thread's 8 channels ----
    float afr[8], w80r[8], w81r[8];
    {
        float4 t0 = *(const float4*)&Afeat[node * H_ + c0];
        float4 t1 = *(const float4*)&Afeat[node * H_ + c0 + 4];
        afr[0]=t0.x; afr[1]=t0.y; afr[2]=t0.z; afr[3]=t0.w;
        afr[4]=t1.x; afr[5]=t1.y; afr[6]=t1.z; afr[7]=t1.w;
        t0 = *(const float4*)&We1[80 * H_ + c0];
        t1 = *(const float4*)&We1[80 * H_ + c0 + 4];
        w80r[0]=t0.x; w80r[1]=t0.y; w80r[2]=t0.z; w80r[3]=t0.w;
        w80r[4]=t1.x; w80r[5]=t1.y; w80r[6]=t1.z; w80r[7]=t1.w;
        t0 = *(const float4*)&We1[81 * H_ + c0];
        t1 = *(const float4*)&We1[81 * H_ + c0 + 4];
        w81r[0]=t0.x; w81r[1]=t0.y; w81r[2]=t0.z; w81r[3]=t0.w;
        w81r[4]=t1.x; w81r[5]=t1.y; w81r[6]=t1.z; w81r[7]=t1.w;
    }

    // ---- epilogue constants + hoisted We2 b-frags (L1-cached global) ----
    int ctb = w * 2;
    float b2r0 = be2[ctb * 16 + l15],  b2r1 = be2[ctb * 16 + 16 + l15];
    float wc0  = Wc[ctb * 16 + l15],   wc1  = Wc[ctb * 16 + 16 + l15];
    const unsigned short* bb0 = we2t + (ctb * 16 + l15) * H_ + qd * 8;
    const unsigned short* bb1 = bb0 + 16 * H_;
    short8 bf00 = *(const short8*)(bb0 +  0);
    short8 bf01 = *(const short8*)(bb0 + 32);
    short8 bf02 = *(const short8*)(bb0 + 64);
    short8 bf03 = *(const short8*)(bb0 + 96);
    short8 bf10 = *(const short8*)(bb1 +  0);
    short8 bf11 = *(const short8*)(bb1 + 32);
    short8 bf12 = *(const short8*)(bb1 + 64);
    short8 bf13 = *(const short8*)(bb1 + 96);

    __syncthreads();   // drains tile-0 DMA (vmcnt 0) + diffE/dbL visible

    // ---- Dsum[d] = sum_j diff (wave 0) ----
    if (w == 0) {
        float p0 = 0, p1 = 0, p2 = 0;
        for (int j = lane; j < NP_; j += 64) {
            float4 d = diffE[j];
            p0 += d.x; p1 += d.y; p2 += d.z;
        }
        for (int s = 1; s < 64; s <<= 1) {
            p0 += __shfl_xor(p0, s, 64);
            p1 += __shfl_xor(p1, s, 64);
            p2 += __shfl_xor(p2, s, 64);
        }
        if (lane == 0) { DsumL[0] = p0; DsumL[1] = p1; DsumL[2] = p2; }
    }

    float aggP0 = 0, aggP1 = 0;
    float SP00 = 0, SP01 = 0, SP02 = 0, SP10 = 0, SP11 = 0, SP12 = 0;

    for (int jt = 0; jt < 10; jt++) {
        short* mb = mbuf[jt & 1];
        const float* bp = bpref[jt & 1];
        // wait for this tile's DMA (issued ~MFMA+epilogue ago; mostly done)
        asm volatile("s_waitcnt vmcnt(0)" ::: "memory");
        // ---- m-compute: this thread's row (rowLoc), 8 channels, from LDS ----
        int jrow = jt * 16 + rowLoc;
        float mv[8];
        if (jrow < N_) {
            float4 b0 = *(const float4*)&bp[rdOff0];
            float4 b1 = *(const float4*)&bp[rdOff1];
            float br[8] = {b0.x, b0.y, b0.z, b0.w, b1.x, b1.y, b1.z, b1.w};
            float2 db = dbL[jrow];
#pragma unroll
            for (int u = 0; u < 8; u++)
                mv[u] = silu_f(afr[u] + br[u] + db.x * w80r[u] + db.y * w81r[u]);
        } else {
#pragma unroll
            for (int u = 0; u < 8; u++) mv[u] = 0.0f;
        }
        uint4 pk;
        pk.x = cvt_pk_bf16(mv[0], mv[1]);
        pk.y = cvt_pk_bf16(mv[2], mv[3]);
        pk.z = cvt_pk_bf16(mv[4], mv[5]);
        pk.w = cvt_pk_bf16(mv[6], mv[7]);
        *(uint4*)&mb[rowLoc * MPQ + c0] = pk;
        __syncthreads();

        // ---- issue next tile's DMA (flies under MFMA+epilogue) ----
        if (jt < 9) {
            const float* nb = bbase + (jt + 1) * 2048;
            float* pd = bpref[(jt + 1) & 1];
            g2lds16(nb + sOffA, pd + w * 512);
            g2lds16(nb + sOffB, pd + w * 512 + 256);
        }

        // ---- MFMA [16j x 128k] @ [128k x 32c per wave] ----
        const short* arow = &mb[l15 * MPQ + qd * 8];
        short8 a0 = *(const short8*)(arow +  0);
        short8 a1 = *(const short8*)(arow + 32);
        short8 a2 = *(const short8*)(arow + 64);
        short8 a3 = *(const short8*)(arow + 96);
        float4v acc0 = {0, 0, 0, 0}, acc1 = {0, 0, 0, 0};
        acc0 = __builtin_amdgcn_mfma_f32_16x16x32_bf16(a0, bf00, acc0, 0, 0, 0);
        acc1 = __builtin_amdgcn_mfma_f32_16x16x32_bf16(a0, bf10, acc1, 0, 0, 0);
        acc0 = __builtin_amdgcn_mfma_f32_16x16x32_bf16(a1, bf01, acc0, 0, 0, 0);
        acc1 = __builtin_amdgcn_mfma_f32_16x16x32_bf16(a1, bf11, acc1, 0, 0, 0);
        acc0 = __builtin_amdgcn_mfma_f32_16x16x32_bf16(a2, bf02, acc0, 0, 0, 0);
        acc1 = __builtin_amdgcn_mfma_f32_16x16x32_bf16(a2, bf12, acc1, 0, 0, 0);
        acc0 = __builtin_amdgcn_mfma_f32_16x16x32_bf16(a3, bf03, acc0, 0, 0, 0);
        acc1 = __builtin_amdgcn_mfma_f32_16x16x32_bf16(a3, bf13, acc1, 0, 0, 0);

        // ---- epilogue: silu, mask, reduce over rows ----
#pragma unroll
        for (int r = 0; r < 4; r++) {
            int j = jt * 16 + qd * 4 + r;
            float4 de = diffE[j];
            float mv0 = silu_f(acc0[r] + b2r0) * de.w;
            float mv1 = silu_f(acc1[r] + b2r1) * de.w;
            aggP0 += mv0; aggP1 += mv1;
            SP00 += de.x * mv0; SP01 += de.y * mv0; SP02 += de.z * mv0;
            SP10 += de.x * mv1; SP11 += de.y * mv1; SP12 += de.z * mv1;
        }
    }

    // ---- cross-quad reduction (rows live in quads) ----
#define QR_(v) { v += __shfl_xor(v, 16, 64); v += __shfl_xor(v, 32, 64); }
    QR_(aggP0) QR_(aggP1)
    QR_(SP00) QR_(SP01) QR_(SP02)
    QR_(SP10) QR_(SP11) QR_(SP12)
#undef QR_

    // agg stays in LDS for the fused node tail (no global round-trip)
    if (!final_mode) {
        if (qd == 0) {
            catL[F_ + ctb * 16 + l15]      = aggP0;
            catL[F_ + ctb * 16 + 16 + l15] = aggP1;
        }
        if (tid < F_) catL[tid] = h_in[node * F_ + tid];
    }

    // deferred cw: x_d += (sum_c Wc[c]*S[d][c] + bc*Dsum[d]) / (N-1)
    float p0 = wc0 * SP00 + wc1 * SP10;
    float p1 = wc0 * SP01 + wc1 * SP11;
    float p2 = wc0 * SP02 + wc1 * SP12;
    for (int s = 1; s < 16; s <<= 1) {
        p0 += __shfl_xor(p0, s, 64);
        p1 += __shfl_xor(p1, s, 64);
        p2 += __shfl_xor(p2, s, 64);
    }
    if (lane == 0) { wpart[w][0] = p0; wpart[w][1] = p1; wpart[w][2] = p2; }
    __syncthreads();
    if (tid < 3) {
        float tot = wpart[0][tid] + wpart[1][tid] + wpart[2][tid] + wpart[3][tid]
                  + bcp[0] * DsumL[tid];
        float xn = x_in[node * 3 + tid] + tot * (1.0f / (float)(N_ - 1));
        if (final_mode)
            x_out[node * 3 + tid] = (xn - x0v[node * 3 + tid]) * amask[b * N_ + i];
        else
            x_out[node * 3 + tid] = xn;
    }

    if (final_mode) return;

    // ---- fused node layer: h_out = silu([h,agg]@Wh+bh); Af/Bf for next layer ----
    if (tid < 120) {
        int f = tid % 40, ks = tid / 40;   // 3-way k-split of 168 = 3*56
        int k0 = ks * 56;
        const float* wr = whTp + f * 168 + k0;   // contiguous 56 floats
        float p = 0.0f;
#pragma unroll
        for (int k = 0; k < 56; k += 4) {
            float4 wv = *(const float4*)(wr + k);
            p += catL[k0 + k]     * wv.x;
            p += catL[k0 + k + 1] * wv.y;
            p += catL[k0 + k + 2] * wv.z;
            p += catL[k0 + k + 3] * wv.w;
        }
        partL[tid] = p;
    }
    __syncthreads();
    if (tid < F_) {
        float hv = silu_f(partL[tid] + partL[40 + tid] + partL[80 + tid] + bh[tid]);
        hnewL[tid] = hv;
        h_out[node * F_ + tid] = hv;
    }
    __syncthreads();
    {
        // fa on tid<128, fb on tid>=128; w1nT contiguous float4 loads.
        int c = tid & 127;
        int isB = tid >> 7;
        float acc = isB ? 0.0f
                        : (be1n[c] + (has_t ? tp[b] * wtn[c] + wbtn[c] : 0.0f));
        const float* wr = w1nTp + c * 80 + isB * 40;   // contiguous 40 floats
#pragma unroll
        for (int k = 0; k < 40; k += 4) {
            float4 wv = *(const float4*)(wr + k);
            acc += hnewL[k]     * wv.x;
            acc += hnewL[k + 1] * wv.y;
            acc += hnewL[k + 2] * wv.z;
            acc += hnewL[k + 3] * wv.w;
        }
        (isB ? Bf_out : Af_out)[node * H_ + c] = acc;
    }
}

extern "C" void kernel_launch(void* const* d_in, const int* in_sizes, int n_in,
                              void* d_out, int out_size, void* d_ws, size_t ws_size,
                              hipStream_t stream) {
    const float* t     = (const float*)d_in[0];
    const float* x     = (const float*)d_in[1];
    const int*   pep   = (const int*)d_in[2];
    const int*   labels= (const int*)d_in[3];
    const int*   aapos = (const int*)d_in[4];
    const float* bond  = (const float*)d_in[5];
    const float* em    = (const float*)d_in[6];
    const float* amask = (const float*)d_in[7];
    const float* R     = (const float*)d_in[8];
    const float* W_e1  = (const float*)d_in[9];
    const float* b_e1  = (const float*)d_in[10];
    const float* W_e2  = (const float*)d_in[11];
    const float* b_e2  = (const float*)d_in[12];
    const float* W_c   = (const float*)d_in[13];
    const float* b_c   = (const float*)d_in[14];
    const float* W_h   = (const float*)d_in[15];
    const float* b_h   = (const float*)d_in[16];
    const float* w_t   = (const float*)d_in[17];
    const float* w_b_t = (const float*)d_in[18];
    const float* tW_e1 = (const float*)d_in[19];
    const float* tb_e1 = (const float*)d_in[20];
    const float* tW_e2 = (const float*)d_in[21];
    const float* tb_e2 = (const float*)d_in[22];
    const float* tW_c  = (const float*)d_in[23];
    const float* tb_c  = (const float*)d_in[24];
    float* out = (float*)d_out;

    float* ws = (float*)d_ws;
    unsigned short* we2t = (unsigned short*)ws;   // 49152 shorts = 24576 floats
    float* x0   = ws + 24576;          // 7200
    float* xA   = x0 + 7200;           // 7200
    float* xB   = xA + 7200;           // 7200
    float* hA   = xB + 7200;           // 96000
    float* hB   = hA + 96000;          // 96000
    float* Af1  = hB + 96000;          // 307200
    float* Bf1  = Af1 + 307200;        // 307200
    float* Af2  = Bf1 + 307200;        // 307200
    float* Bf2  = Af2 + 307200;        // 307200
    float* whT  = Bf2 + 307200;        // 13440  (2 layers x [40][168])
    float* w1nT = whT + 13440;         // 20480  (2 x [128][80])

    prelude_kernel<<<504, 256, 0, stream>>>(W_e2, tW_e2, we2t, x, R, xA, x0,
                                            pep, labels, aapos, W_e1, b_e1,
                                            t, w_t, w_b_t, hA, Af1, Bf1,
                                            W_h, whT,
                                            W_e1 + EF_ * H_, tW_e1, w1nT);

    // ---- layer 0 (edge + fused node -> layer-1 feats) ----
    edge_fused_kernel<<<NB_, 256, 0, stream>>>(
        xA, Af1, Bf1, W_e1, we2t, b_e2, W_c, b_c, bond, em,
        hA, whT, b_h, w1nT, b_e1 + H_, t, w_t + H_, w_b_t + H_, 1,
        nullptr, nullptr, 0,
        xB, hB, Af2, Bf2);

    // ---- layer 1 (edge + fused node -> t-layer feats) ----
    edge_fused_kernel<<<NB_, 256, 0, stream>>>(
        xB, Af2, Bf2, W_e1 + EF_ * H_, we2t + 16384, b_e2 + H_, W_c + H_, b_c + 1,
        bond, em,
        hB, whT + 6720, b_h + F_, w1nT + 10240, tb_e1, nullptr, nullptr, nullptr, 0,
        nullptr, nullptr, 0,
        xA, hA, Af1, Bf1);

    // ---- t layer: fused final output (no node tail) ----
    edge_fused_kernel<<<NB_, 256, 0, stream>>>(
        xA, Af1, Bf1, tW_e1, we2t + 32768, tb_e2, tW_c, tb_c, bond, em,
        nullptr, nullptr, nullptr, nullptr, nullptr, nullptr, nullptr, nullptr, 0,
        x0, amask, 1,
        out, nullptr, nullptr, nullptr);
}

// Round 9
// 262.704 us; speedup vs baseline: 1.0119x; 1.0119x over previous
//
#include <hip/hip_runtime.h>
#include <math.h>

#define B_ 2
#define S_ 8
#define N_ 150
#define H_ 128
#define F_ 40
#define EF_ 82
#define NP_ 160            // N padded to 10 j-tiles of 16
#define MPQ 136            // mbuf row pitch in bf16 elems (128 + 8 pad)
#define NB_ 2400           // B*S*N

typedef __attribute__((ext_vector_type(8))) short short8;
typedef __attribute__((ext_vector_type(4))) float float4v;

__device__ __forceinline__ float silu_f(float v) {
    return v * __builtin_amdgcn_rcpf(1.0f + __expf(-v));
}

// fp32 -> bf16 bits, round-to-nearest-even (prelude pack; matches v_cvt_pk_bf16_f32)
__device__ __forceinline__ unsigned short f2bf(float f) {
    unsigned u = __builtin_bit_cast(unsigned, f);
    return (unsigned short)((u + 0x7fffu + ((u >> 16) & 1u)) >> 16);
}

// HW RNE pack: lo -> bits[15:0], hi -> bits[31:16]. Identical rounding to f2bf
// for all finite values (both RNE); silu outputs are always finite.
__device__ __forceinline__ unsigned cvt_pk_bf16(float lo, float hi) {
    unsigned r;
    asm("v_cvt_pk_bf16_f32 %0, %1, %2" : "=v"(r) : "v"(lo), "v"(hi));
    return r;
}

// ---------------- prelude: pack_we2 + restore_x + node0 + WhT + W1nT ----------
// blocks [0,192):   pack 3 layers' We2 -> bf16 transposed [c][k]
// blocks [192,221): restore absolute coords (7200 elems)
// blocks [221,371): layer-0 node embedding (2 (b,i) per block)
// blocks [371,424): pack WhT[l][f][k] = W_h[l][k][f]      (2*40*168)
// blocks [424,504): pack W1nT[s][c][k] = We1_s[k][c], k<80 (2*128*80)
__global__ void prelude_kernel(const float* __restrict__ W_e2,
                               const float* __restrict__ tW_e2,
                               unsigned short* __restrict__ we2t,
                               const float* __restrict__ x,
                               const float* __restrict__ R,
                               float* __restrict__ xa,
                               float* __restrict__ x0,
                               const int* __restrict__ pep,
                               const int* __restrict__ labels,
                               const int* __restrict__ aapos,
                               const float* __restrict__ We1,
                               const float* __restrict__ be1,
                               const float* __restrict__ tp,
                               const float* __restrict__ wt,
                               const float* __restrict__ wbt,
                               float* __restrict__ h0,
                               float* __restrict__ Af,
                               float* __restrict__ Bf,
                               const float* __restrict__ W_h,
                               float* __restrict__ whT,
                               const float* __restrict__ We1L1,
                               const float* __restrict__ tWe1,
                               float* __restrict__ w1nT) {
    int bid = blockIdx.x;
    int tid = threadIdx.x;
    if (bid < 192) {
        int e = bid * 256 + tid;                 // 0..49151
        int l = e >> 14, idx = e & 16383;
        int k = idx >> 7, c = idx & 127;
        const float* src = (l == 0) ? W_e2 : (l == 1) ? (W_e2 + H_ * H_) : tW_e2;
        we2t[l * 16384 + c * H_ + k] = f2bf(src[idx]);
    } else if (bid < 221) {
        int idx = (bid - 192) * 256 + tid;
        if (idx < B_ * S_ * N_ * 3) {
            int d = idx % 3;
            int i = (idx / 3) % N_;
            int bs = idx / (3 * N_);
            int b = bs / S_;
            const float* xrow = x + bs * N_ * 3 + d;
            const float* Rrow = R + (b * N_ + i) * N_;
            float acc = 0.0f;
            for (int j = 0; j < N_; j++) acc += xrow[j * 3] * Rrow[j];
            xa[idx] = acc;
            x0[idx] = acc;
        }
    } else if (bid < 371) {
        int rel = bid - 221;                     // 0..149
        int bi = rel * 2 + (tid >> 7);           // 0..299
        int b = bi / N_, i = bi % N_;
        int c = tid & 127;
        int al = labels[bi];
        int ap = aapos[bi];                      // 1..15
        int aa = pep[b * 15 + ap - 1];
        int r0 = al, r1 = 5 + aa, r2 = 25 + ap - 1;
        float fa = We1[r0 * H_ + c] + We1[r1 * H_ + c] + We1[r2 * H_ + c]
                 + be1[c] + tp[b] * wt[c] + wbt[c];
        float fb = We1[(F_ + r0) * H_ + c] + We1[(F_ + r1) * H_ + c] + We1[(F_ + r2) * H_ + c];
        float hv = 0.0f;
        if (c < F_) hv = (c == r0 || c == r1 || c == r2) ? 1.0f : 0.0f;
        for (int s = 0; s < S_; s++) {
            int n = (b * S_ + s) * N_ + i;
            Af[n * H_ + c] = fa;
            Bf[n * H_ + c] = fb;
            if (c < F_) h0[n * F_ + c] = hv;
        }
    } else if (bid < 424) {
        int e = (bid - 371) * 256 + tid;         // 0..13567
        if (e < 2 * F_ * 168) {
            int l = e / 6720, idx = e % 6720;
            int f = idx / 168, k = idx % 168;
            whT[l * 6720 + f * 168 + k] = W_h[l * 6720 + k * F_ + f];
        }
    } else {
        int e = (bid - 424) * 256 + tid;         // 0..20479 exact
        int s = e / 10240, idx = e % 10240;
        int c = idx / 80, k = idx % 80;
        const float* src = s ? tWe1 : We1L1;
        w1nT[s * 10240 + c * 80 + k] = src[k * H_ + c];
    }
}

// ---------------- fused edge + node: block per (bs,i) ----------------
// EXACT r7 structure (16-row tiles, 10 barriers, dbuf mbuf, cvt_pk pack,
// VGPR 60, no spill). ONE change: s_setprio(1) around the MFMA cluster (T5)
// — runtime wave arbitration; applies because independent blocks co-resident
// on a CU sit at different phases (m191 regime). Zero register/numerics
// impact. r8's LDS-DMA prefetch reverted (null: latency already TLP-hidden).
__global__ __launch_bounds__(256, 4) void edge_fused_kernel(
    const float* __restrict__ x_in,    // [BS*N,3]
    const float* __restrict__ Afeat,   // [BS*N,128]
    const float* __restrict__ Bfeat,   // [BS*N,128]
    const float* __restrict__ We1,     // [82,128] rows 80/81 (dist,bond cols)
    const unsigned short* __restrict__ we2t,  // [128c][128k] bf16
    const float* __restrict__ be2,
    const float* __restrict__ Wc,
    const float* __restrict__ bcp,
    const float* __restrict__ bond,
    const float* __restrict__ emask,
    const float* __restrict__ h_in,    // [BS*N,40]      (node tail)
    const float* __restrict__ whTp,    // [40][168]      (node tail, transposed Wh)
    const float* __restrict__ bh,      // [40]           (node tail)
    const float* __restrict__ w1nTp,   // [128][80]      (next layer We1 rows 0..79, transposed)
    const float* __restrict__ be1n,
    const float* __restrict__ tp,
    const float* __restrict__ wtn,
    const float* __restrict__ wbtn,
    int has_t,
    const float* __restrict__ x0v,     // final mode only
    const float* __restrict__ amask,   // final mode only
    int final_mode,
    float* __restrict__ x_out,         // xnew, or final output
    float* __restrict__ h_out,         // node tail out
    float* __restrict__ Af_out,        // node tail out (next layer)
    float* __restrict__ Bf_out)        // node tail out (next layer)
{
    __shared__ __align__(16) short mbuf[2][16 * MPQ];   // 8.7 KB
    __shared__ float4 diffE[NP_];                       // d0,d1,d2,em
    __shared__ float2 dbL[NP_];                         // dist, bond
    __shared__ float DsumL[3];
    __shared__ float wpart[4][3];
    __shared__ float catL[F_ + H_];                     // [h(40), agg(128)]
    __shared__ float partL[120];
    __shared__ float hnewL[F_];

    int blk = blockIdx.x;
    int i = blk % N_, bs = blk / N_, b = bs / S_;
    int tid = threadIdx.x;
    int node = bs * N_ + i;
    int lane = tid & 63, w = tid >> 6;
    int qd = lane >> 4, l15 = lane & 15;
    int rowLoc = tid >> 4, c0 = (tid & 15) * 8;

    float xi0 = x_in[node * 3 + 0];
    float xi1 = x_in[node * 3 + 1];
    float xi2 = x_in[node * 3 + 2];

    // ---- stage per-j scalars ----
    if (tid < NP_) {
        int j = tid;
        float xj0 = xi0, xj1 = xi1, xj2 = xi2, bnd = 0.0f, emv = 0.0f;
        if (j < N_) {
            int nj = bs * N_ + j;
            xj0 = x_in[nj * 3 + 0];
            xj1 = x_in[nj * 3 + 1];
            xj2 = x_in[nj * 3 + 2];
            int eij = (b * N_ + i) * N_ + j;
            bnd = bond[eij];
            emv = (j == i) ? 0.0f : emask[eij];
        }
        float d0 = xi0 - xj0, d1 = xi1 - xj1, d2 = xi2 - xj2;
        diffE[j] = make_float4(d0, d1, d2, emv);
        dbL[j] = make_float2(sqrtf(d0 * d0 + d1 * d1 + d2 * d2 + 1e-12f), bnd);
    }

    // ---- hoisted m-compute constants: this thread's 8 channels ----
    float afr[8], w80r[8], w81r[8];
    {
        float4 t0 = *(const float4*)&Afeat[node * H_ + c0];
        float4 t1 = *(const float4*)&Afeat[node * H_ + c0 + 4];
        afr[0]=t0.x; afr[1]=t0.y; afr[2]=t0.z; afr[3]=t0.w;
        afr[4]=t1.x; afr[5]=t1.y; afr[6]=t1.z; afr[7]=t1.w;
        t0 = *(const float4*)&We1[80 * H_ + c0];
        t1 = *(const float4*)&We1[80 * H_ + c0 + 4];
        w80r[0]=t0.x; w80r[1]=t0.y; w80r[2]=t0.z; w80r[3]=t0.w;
        w80r[4]=t1.x; w80r[5]=t1.y; w80r[6]=t1.z; w80r[7]=t1.w;
        t0 = *(const float4*)&We1[81 * H_ + c0];
        t1 = *(const float4*)&We1[81 * H_ + c0 + 4];
        w81r[0]=t0.x; w81r[1]=t0.y; w81r[2]=t0.z; w81r[3]=t0.w;
        w81r[4]=t1.x; w81r[5]=t1.y; w81r[6]=t1.z; w81r[7]=t1.w;
    }

    // ---- epilogue constants + hoisted We2 b-frags (L1-cached global) ----
    int ctb = w * 2;
    float b2r0 = be2[ctb * 16 + l15],  b2r1 = be2[ctb * 16 + 16 + l15];
    float wc0  = Wc[ctb * 16 + l15],   wc1  = Wc[ctb * 16 + 16 + l15];
    const unsigned short* bb0 = we2t + (ctb * 16 + l15) * H_ + qd * 8;
    const unsigned short* bb1 = bb0 + 16 * H_;
    short8 bf00 = *(const short8*)(bb0 +  0);
    short8 bf01 = *(const short8*)(bb0 + 32);
    short8 bf02 = *(const short8*)(bb0 + 64);
    short8 bf03 = *(const short8*)(bb0 + 96);
    short8 bf10 = *(const short8*)(bb1 +  0);
    short8 bf11 = *(const short8*)(bb1 + 32);
    short8 bf12 = *(const short8*)(bb1 + 64);
    short8 bf13 = *(const short8*)(bb1 + 96);

    __syncthreads();

    // ---- Dsum[d] = sum_j diff (wave 0) ----
    if (w == 0) {
        float p0 = 0, p1 = 0, p2 = 0;
        for (int j = lane; j < NP_; j += 64) {
            float4 d = diffE[j];
            p0 += d.x; p1 += d.y; p2 += d.z;
        }
        for (int s = 1; s < 64; s <<= 1) {
            p0 += __shfl_xor(p0, s, 64);
            p1 += __shfl_xor(p1, s, 64);
            p2 += __shfl_xor(p2, s, 64);
        }
        if (lane == 0) { DsumL[0] = p0; DsumL[1] = p1; DsumL[2] = p2; }
    }

    float aggP0 = 0, aggP1 = 0;
    float SP00 = 0, SP01 = 0, SP02 = 0, SP10 = 0, SP11 = 0, SP12 = 0;

    for (int jt = 0; jt < 10; jt++) {
        short* mb = mbuf[jt & 1];
        // ---- m-compute: this thread's row (rowLoc), 8 channels ----
        int jrow = jt * 16 + rowLoc;
        float mv[8];
        if (jrow < N_) {
            const float* bp = &Bfeat[(bs * N_ + jrow) * H_ + c0];
            float4 b0 = *(const float4*)bp;
            float4 b1 = *(const float4*)(bp + 4);
            float br[8] = {b0.x, b0.y, b0.z, b0.w, b1.x, b1.y, b1.z, b1.w};
            float2 db = dbL[jrow];
#pragma unroll
            for (int u = 0; u < 8; u++)
                mv[u] = silu_f(afr[u] + br[u] + db.x * w80r[u] + db.y * w81r[u]);
        } else {
#pragma unroll
            for (int u = 0; u < 8; u++) mv[u] = 0.0f;
        }
        uint4 pk;
        pk.x = cvt_pk_bf16(mv[0], mv[1]);
        pk.y = cvt_pk_bf16(mv[2], mv[3]);
        pk.z = cvt_pk_bf16(mv[4], mv[5]);
        pk.w = cvt_pk_bf16(mv[6], mv[7]);
        *(uint4*)&mb[rowLoc * MPQ + c0] = pk;
        __syncthreads();

        // ---- MFMA [16j x 128k] @ [128k x 32c per wave] ----
        const short* arow = &mb[l15 * MPQ + qd * 8];
        short8 a0 = *(const short8*)(arow +  0);
        short8 a1 = *(const short8*)(arow + 32);
        short8 a2 = *(const short8*)(arow + 64);
        short8 a3 = *(const short8*)(arow + 96);
        float4v acc0 = {0, 0, 0, 0}, acc1 = {0, 0, 0, 0};
        __builtin_amdgcn_s_setprio(1);
        acc0 = __builtin_amdgcn_mfma_f32_16x16x32_bf16(a0, bf00, acc0, 0, 0, 0);
        acc1 = __builtin_amdgcn_mfma_f32_16x16x32_bf16(a0, bf10, acc1, 0, 0, 0);
        acc0 = __builtin_amdgcn_mfma_f32_16x16x32_bf16(a1, bf01, acc0, 0, 0, 0);
        acc1 = __builtin_amdgcn_mfma_f32_16x16x32_bf16(a1, bf11, acc1, 0, 0, 0);
        acc0 = __builtin_amdgcn_mfma_f32_16x16x32_bf16(a2, bf02, acc0, 0, 0, 0);
        acc1 = __builtin_amdgcn_mfma_f32_16x16x32_bf16(a2, bf12, acc1, 0, 0, 0);
        acc0 = __builtin_amdgcn_mfma_f32_16x16x32_bf16(a3, bf03, acc0, 0, 0, 0);
        acc1 = __builtin_amdgcn_mfma_f32_16x16x32_bf16(a3, bf13, acc1, 0, 0, 0);
        __builtin_amdgcn_s_setprio(0);

        // ---- epilogue: silu, mask, reduce over rows ----
#pragma unroll
        for (int r = 0; r < 4; r++) {
            int j = jt * 16 + qd * 4 + r;
            float4 de = diffE[j];
            float mv0 = silu_f(acc0[r] + b2r0) * de.w;
            float mv1 = silu_f(acc1[r] + b2r1) * de.w;
            aggP0 += mv0; aggP1 += mv1;
            SP00 += de.x * mv0; SP01 += de.y * mv0; SP02 += de.z * mv0;
            SP10 += de.x * mv1; SP11 += de.y * mv1; SP12 += de.z * mv1;
        }
    }

    // ---- cross-quad reduction (rows live in quads) ----
#define QR_(v) { v += __shfl_xor(v, 16, 64); v += __shfl_xor(v, 32, 64); }
    QR_(aggP0) QR_(aggP1)
    QR_(SP00) QR_(SP01) QR_(SP02)
    QR_(SP10) QR_(SP11) QR_(SP12)
#undef QR_

    // agg stays in LDS for the fused node tail (no global round-trip)
    if (!final_mode) {
        if (qd == 0) {
            catL[F_ + ctb * 16 + l15]      = aggP0;
            catL[F_ + ctb * 16 + 16 + l15] = aggP1;
        }
        if (tid < F_) catL[tid] = h_in[node * F_ + tid];
    }

    // deferred cw: x_d += (sum_c Wc[c]*S[d][c] + bc*Dsum[d]) / (N-1)
    float p0 = wc0 * SP00 + wc1 * SP10;
    float p1 = wc0 * SP01 + wc1 * SP11;
    float p2 = wc0 * SP02 + wc1 * SP12;
    for (int s = 1; s < 16; s <<= 1) {
        p0 += __shfl_xor(p0, s, 64);
        p1 += __shfl_xor(p1, s, 64);
        p2 += __shfl_xor(p2, s, 64);
    }
    if (lane == 0) { wpart[w][0] = p0; wpart[w][1] = p1; wpart[w][2] = p2; }
    __syncthreads();
    if (tid < 3) {
        float tot = wpart[0][tid] + wpart[1][tid] + wpart[2][tid] + wpart[3][tid]
                  + bcp[0] * DsumL[tid];
        float xn = x_in[node * 3 + tid] + tot * (1.0f / (float)(N_ - 1));
        if (final_mode)
            x_out[node * 3 + tid] = (xn - x0v[node * 3 + tid]) * amask[b * N_ + i];
        else
            x_out[node * 3 + tid] = xn;
    }

    if (final_mode) return;

    // ---- fused node layer: h_out = silu([h,agg]@Wh+bh); Af/Bf for next layer ----
    if (tid < 120) {
        int f = tid % 40, ks = tid / 40;   // 3-way k-split of 168 = 3*56
        int k0 = ks * 56;
        const float* wr = whTp + f * 168 + k0;   // contiguous 56 floats
        float p = 0.0f;
#pragma unroll
        for (int k = 0; k < 56; k += 4) {
            float4 wv = *(const float4*)(wr + k);
            p += catL[k0 + k]     * wv.x;
            p += catL[k0 + k + 1] * wv.y;
            p += catL[k0 + k + 2] * wv.z;
            p += catL[k0 + k + 3] * wv.w;
        }
        partL[tid] = p;
    }
    __syncthreads();
    if (tid < F_) {
        float hv = silu_f(partL[tid] + partL[40 + tid] + partL[80 + tid] + bh[tid]);
        hnewL[tid] = hv;
        h_out[node * F_ + tid] = hv;
    }
    __syncthreads();
    {
        // fa on tid<128, fb on tid>=128; w1nT contiguous float4 loads.
        int c = tid & 127;
        int isB = tid >> 7;
        float acc = isB ? 0.0f
                        : (be1n[c] + (has_t ? tp[b] * wtn[c] + wbtn[c] : 0.0f));
        const float* wr = w1nTp + c * 80 + isB * 40;   // contiguous 40 floats
#pragma unroll
        for (int k = 0; k < 40; k += 4) {
            float4 wv = *(const float4*)(wr + k);
            acc += hnewL[k]     * wv.x;
            acc += hnewL[k + 1] * wv.y;
            acc += hnewL[k + 2] * wv.z;
            acc += hnewL[k + 3] * wv.w;
        }
        (isB ? Bf_out : Af_out)[node * H_ + c] = acc;
    }
}

extern "C" void kernel_launch(void* const* d_in, const int* in_sizes, int n_in,
                              void* d_out, int out_size, void* d_ws, size_t ws_size,
                              hipStream_t stream) {
    const float* t     = (const float*)d_in[0];
    const float* x     = (const float*)d_in[1];
    const int*   pep   = (const int*)d_in[2];
    const int*   labels= (const int*)d_in[3];
    const int*   aapos = (const int*)d_in[4];
    const float* bond  = (const float*)d_in[5];
    const float* em    = (const float*)d_in[6];
    const float* amask = (const float*)d_in[7];
    const float* R     = (const float*)d_in[8];
    const float* W_e1  = (const float*)d_in[9];
    const float* b_e1  = (const float*)d_in[10];
    const float* W_e2  = (const float*)d_in[11];
    const float* b_e2  = (const float*)d_in[12];
    const float* W_c   = (const float*)d_in[13];
    const float* b_c   = (const float*)d_in[14];
    const float* W_h   = (const float*)d_in[15];
    const float* b_h   = (const float*)d_in[16];
    const float* w_t   = (const float*)d_in[17];
    const float* w_b_t = (const float*)d_in[18];
    const float* tW_e1 = (const float*)d_in[19];
    const float* tb_e1 = (const float*)d_in[20];
    const float* tW_e2 = (const float*)d_in[21];
    const float* tb_e2 = (const float*)d_in[22];
    const float* tW_c  = (const float*)d_in[23];
    const float* tb_c  = (const float*)d_in[24];
    float* out = (float*)d_out;

    float* ws = (float*)d_ws;
    unsigned short* we2t = (unsigned short*)ws;   // 49152 shorts = 24576 floats
    float* x0   = ws + 24576;          // 7200
    float* xA   = x0 + 7200;           // 7200
    float* xB   = xA + 7200;           // 7200
    float* hA   = xB + 7200;           // 96000
    float* hB   = hA + 96000;          // 96000
    float* Af1  = hB + 96000;          // 307200
    float* Bf1  = Af1 + 307200;        // 307200
    float* Af2  = Bf1 + 307200;        // 307200
    float* Bf2  = Af2 + 307200;        // 307200
    float* whT  = Bf2 + 307200;        // 13440  (2 layers x [40][168])
    float* w1nT = whT + 13440;         // 20480  (2 x [128][80])

    prelude_kernel<<<504, 256, 0, stream>>>(W_e2, tW_e2, we2t, x, R, xA, x0,
                                            pep, labels, aapos, W_e1, b_e1,
                                            t, w_t, w_b_t, hA, Af1, Bf1,
                                            W_h, whT,
                                            W_e1 + EF_ * H_, tW_e1, w1nT);

    // ---- layer 0 (edge + fused node -> layer-1 feats) ----
    edge_fused_kernel<<<NB_, 256, 0, stream>>>(
        xA, Af1, Bf1, W_e1, we2t, b_e2, W_c, b_c, bond, em,
        hA, whT, b_h, w1nT, b_e1 + H_, t, w_t + H_, w_b_t + H_, 1,
        nullptr, nullptr, 0,
        xB, hB, Af2, Bf2);

    // ---- layer 1 (edge + fused node -> t-layer feats) ----
    edge_fused_kernel<<<NB_, 256, 0, stream>>>(
        xB, Af2, Bf2, W_e1 + EF_ * H_, we2t + 16384, b_e2 + H_, W_c + H_, b_c + 1,
        bond, em,
        hB, whT + 6720, b_h + F_, w1nT + 10240, tb_e1, nullptr, nullptr, nullptr, 0,
        nullptr, nullptr, 0,
        xA, hA, Af1, Bf1);

    // ---- t layer: fused final output (no node tail) ----
    edge_fused_kernel<<<NB_, 256, 0, stream>>>(
        xA, Af1, Bf1, tW_e1, we2t + 32768, tb_e2, tW_c, tb_c, bond, em,
        nullptr, nullptr, nullptr, nullptr, nullptr, nullptr, nullptr, nullptr, 0,
        x0, amask, 1,
        out, nullptr, nullptr, nullptr);
}